// Round 1
// baseline (403.508 us; speedup 1.0000x reference)
//
#include <hip/hip_runtime.h>
#include <hip/hip_bf16.h>

// SCM_39676907888322: sigmoid-gated cross attention. fp32 I/O, bf16 MFMA compute.
// R5: attn rewritten around 32x32x16 MFMA with swapped QK^T:
//  - each wave owns 32 n-rows (halves per-output LDS reads, +20% MFMA rate)
//  - P stays in registers: sigmoid -> v_cvt_pk_bf16_f32 -> v_permlane32_swap_b32
//    builds PV B-frags directly (no P LDS round trip)
//  - m-split-2 keeps grid at 576: wave = (n-strip, m-half); f32 cross-half
//    reduction via LDS at the end
//  - K/V LDS tiles linear + 16B-chunk XOR swizzle (K: ^row&15, V: ^row&7),
//    conflict-free reads; register-double-buffered global prefetch as before

typedef __bf16 bf16;
typedef __bf16 bf16x8 __attribute__((ext_vector_type(8)));
typedef __bf16 bf16x4 __attribute__((ext_vector_type(4)));
typedef float f32x4 __attribute__((ext_vector_type(4)));
typedef float f32x16 __attribute__((ext_vector_type(16)));

#define NB 8
#define NC 256
#define NCI 128
#define NHW 2304
#define NT32 72    // 2304 / 32  (qkv n-tiles)

__global__ __launch_bounds__(256) void wconv_kernel(
    const float* __restrict__ w0, const float* __restrict__ w1,
    const float* __restrict__ w2, const float* __restrict__ w3,
    const float* __restrict__ w4, const float* __restrict__ w5,
    bf16* __restrict__ dst)
{
    int idx = (blockIdx.x * 256 + threadIdx.x) * 8;   // 6*32768 total
    int m = idx >> 15;                                 // matrix id (block-uniform)
    int off = idx & 32767;
    const float* w = (m == 0) ? w0 : (m == 1) ? w1 : (m == 2) ? w2
                   : (m == 3) ? w3 : (m == 4) ? w4 : w5;
    f32x4 a0 = *(const f32x4*)(w + off);
    f32x4 a1 = *(const f32x4*)(w + off + 4);
    bf16x8 o;
    #pragma unroll
    for (int j = 0; j < 4; ++j) { o[j] = (bf16)a0[j]; o[4 + j] = (bf16)a1[j]; }
    *(bf16x8*)(dst + idx) = o;
}

__global__ __launch_bounds__(256) void qkv_kernel(
    const float* __restrict__ x1, const float* __restrict__ x2,
    const bf16* __restrict__ wb,
    const float* __restrict__ bv1, const float* __restrict__ bk1, const float* __restrict__ bq1,
    const float* __restrict__ bv2, const float* __restrict__ bk2, const float* __restrict__ bq2,
    bf16* __restrict__ Qt, bf16* __restrict__ Kt, bf16* __restrict__ Vt,
    float* __restrict__ out)
{
    // Xt[n][c] bf16, 32 rows, padded stride 264
    __shared__ __align__(16) bf16 Xt[32 * 264];

    int gid = blockIdx.x;
    int nt = gid % NT32;
    int s = (gid / NT32) & 1;
    int b = gid / (2 * NT32);
    int n0 = nt * 32;

    const float* x = s ? x2 : x1;
    // wb layout: [v1,k1,q1,v2,k2,q2] each 128*256
    const bf16* wv = wb + (size_t)(s * 3 + 0) * (NCI * NC);
    const bf16* wk = wb + (size_t)(s * 3 + 1) * (NCI * NC);
    const bf16* wq = wb + (size_t)(s * 3 + 2) * (NCI * NC);
    const float* bv = s ? bv2 : bv1;
    const float* bk = s ? bk2 : bk1;
    const float* bq = s ? bq2 : bq1;
    float* outy = out + (size_t)s * (NB * 384 * NHW);

    int tid = threadIdx.x;
    // Stage X tile (256 c x 32 n) into LDS transposed (bf16); fp32 concat passthrough.
    {
        int n_off = (tid & 3) * 8;       // 0,8,16,24
        int c0l = tid >> 2;              // 0..63
        #pragma unroll
        for (int i = 0; i < 4; ++i) {
            int c = c0l + i * 64;
            const float* src = x + ((size_t)(b * NC + c) * NHW + n0 + n_off);
            f32x4 a0 = *(const f32x4*)src;
            f32x4 a1 = *(const f32x4*)(src + 4);
            float* dsty = outy + ((size_t)(b * 384 + c) * NHW + n0 + n_off);
            *(f32x4*)dsty = a0;
            *(f32x4*)(dsty + 4) = a1;
            #pragma unroll
            for (int j = 0; j < 4; ++j) {
                Xt[(n_off + j) * 264 + c] = (bf16)a0[j];
                Xt[(n_off + 4 + j) * 264 + c] = (bf16)a1[j];
            }
        }
    }
    __syncthreads();

    int lane = tid & 63;
    int wid = tid >> 6;                  // wave 0..3 -> ci strip of 32
    int row = lane & 15, quad = lane >> 4;
    int ci_base = wid * 32;

    f32x4 acc[3][2][2];                  // [q,k,v][mi][j]
    #pragma unroll
    for (int t = 0; t < 3; ++t)
        #pragma unroll
        for (int mi = 0; mi < 2; ++mi)
            #pragma unroll
            for (int j = 0; j < 2; ++j)
                acc[t][mi][j] = (f32x4){0.f, 0.f, 0.f, 0.f};

    const bf16* wptr[3] = {wq, wk, wv};
    #pragma unroll
    for (int ks = 0; ks < 8; ++ks) {
        int c0 = ks * 32 + quad * 8;
        bf16x8 bfrag[2];
        #pragma unroll
        for (int j = 0; j < 2; ++j)
            bfrag[j] = *(const bf16x8*)&Xt[(j * 16 + row) * 264 + c0];
        #pragma unroll
        for (int t = 0; t < 3; ++t) {
            #pragma unroll
            for (int mi = 0; mi < 2; ++mi) {
                bf16x8 afrag = *(const bf16x8*)&wptr[t][(size_t)(ci_base + mi * 16 + row) * NC + c0];
                #pragma unroll
                for (int j = 0; j < 2; ++j)
                    acc[t][mi][j] = __builtin_amdgcn_mfma_f32_16x16x32_bf16(
                        afrag, bfrag[j], acc[t][mi][j], 0, 0, 0);
            }
        }
    }

    // Epilogue: +bias (fp32), write Qt/Kt (n,128) bf16 8B stores, V (128,n) bf16 scalar.
    size_t qkbase = ((size_t)s * NB + b) * NHW * NCI;
    size_t vbase  = ((size_t)s * NB + b) * NCI * NHW;
    #pragma unroll
    for (int mi = 0; mi < 2; ++mi) {
        int ci0 = ci_base + mi * 16 + quad * 4;
        f32x4 bq4 = *(const f32x4*)&bq[ci0];
        f32x4 bk4 = *(const f32x4*)&bk[ci0];
        f32x4 bv4 = *(const f32x4*)&bv[ci0];
        #pragma unroll
        for (int j = 0; j < 2; ++j) {
            int n = n0 + j * 16 + row;   // D col = lane&15
            bf16x4 pk;
            #pragma unroll
            for (int r = 0; r < 4; ++r) pk[r] = (bf16)(acc[0][mi][j][r] + bq4[r]);
            *(bf16x4*)&Qt[qkbase + (size_t)n * NCI + ci0] = pk;
            #pragma unroll
            for (int r = 0; r < 4; ++r) pk[r] = (bf16)(acc[1][mi][j][r] + bk4[r]);
            *(bf16x4*)&Kt[qkbase + (size_t)n * NCI + ci0] = pk;
            #pragma unroll
            for (int r = 0; r < 4; ++r)
                Vt[vbase + (size_t)(ci0 + r) * NHW + n] = (bf16)(acc[2][mi][j][r] + bv4[r]);
        }
    }
}

__global__ __launch_bounds__(256, 2) void attn_kernel(
    const bf16* __restrict__ Qt, const bf16* __restrict__ Kt, const bf16* __restrict__ Vt,
    float* __restrict__ out)
{
    // K half-tiles: [2][64 m][128 c] bf16, 16B-chunk swizzle: chunk ^= (mrow & 15)
    // V half-tiles: [2][128 c][64 m] bf16, 16B-chunk swizzle: chunk ^= (crow & 7)
    __shared__ __align__(16) bf16 KH[2 * 64 * 128];   // 32 KB
    __shared__ __align__(16) bf16 VH[2 * 128 * 64];   // 32 KB

    int gid = blockIdx.x;
    // XCD swizzle: gid%8 = XCD slot; both dirs of batch b=gid%8 share an XCD.
    int pair = (gid & 7) * 2 + ((gid >> 3) & 1);   // 0..15
    int nb = gid >> 4;                              // 0..35
    int dir = pair & 1;
    int b = pair >> 1;

    int tid = threadIdx.x;
    int lane = tid & 63;
    int w = tid >> 6;
    int ns = w & 1;        // n-strip (32 rows)
    int mh = w >> 1;       // m-half (m in [mh*1152, mh*1152+1152))
    int col = lane & 31;
    int hi = lane >> 5;

    int sq = dir, skv = dir ^ 1;
    const bf16* q = Qt + ((size_t)sq  * NB + b) * (NHW * NCI);
    const bf16* k = Kt + ((size_t)skv * NB + b) * (NHW * NCI);
    const bf16* v = Vt + ((size_t)skv * NB + b) * (NCI * NHW);
    float* outy = out + (size_t)dir * (NB * 384 * NHW) + ((size_t)b * 384 + 256) * NHW;

    // Staging: per thread 4 chunks (16B) per tile, 4 tiles (K/V x 2 halves).
    int kgoff[4], vgoff[4], kloff[4], vloff[4];
    #pragma unroll
    for (int i = 0; i < 4; ++i) {
        int c = tid + i * 256;
        int kr = c >> 4, kc = c & 15;    // K: 64 rows x 16 chunks
        kgoff[i] = kr * NCI + kc * 8;
        kloff[i] = kr * 128 + ((kc ^ (kr & 15)) * 8);
        int vr = c >> 3, vc = c & 7;     // V: 128 rows x 8 chunks
        vgoff[i] = vr * NHW + vc * 8;
        vloff[i] = vr * 64 + ((vc ^ (vr & 7)) * 8);
    }

    int nw = nb * 64 + ns * 32;          // this wave's 32 Q rows
    bf16x8 qf[8];                        // Q B-frags, resident across m-loop
    #pragma unroll
    for (int kq = 0; kq < 8; ++kq)
        qf[kq] = *(const bf16x8*)&q[(size_t)(nw + col) * NCI + kq * 16 + hi * 8];

    f32x16 o[4];                         // O^T acc: rows c = ct*32+..., col n
    #pragma unroll
    for (int ct = 0; ct < 4; ++ct)
        #pragma unroll
        for (int j = 0; j < 16; ++j) o[ct][j] = 0.f;

    // Prefetch tile 0 (both halves) into registers.
    bf16x8 rk[2][4], rv[2][4];
    #pragma unroll
    for (int h = 0; h < 2; ++h) {
        const bf16* kp = k + (size_t)(h * 1152) * NCI;
        const bf16* vp = v + h * 1152;
        #pragma unroll
        for (int i = 0; i < 4; ++i) {
            rk[h][i] = *(const bf16x8*)(kp + kgoff[i]);
            rv[h][i] = *(const bf16x8*)(vp + vgoff[i]);
        }
    }

    const bf16* KB = &KH[mh * (64 * 128)];
    const bf16* VB = &VH[mh * (128 * 64)];

    for (int it = 0; it < 18; ++it) {
        __syncthreads();                 // prior tile's LDS reads complete
        #pragma unroll
        for (int h = 0; h < 2; ++h)
            #pragma unroll
            for (int i = 0; i < 4; ++i) {
                *(bf16x8*)&KH[h * (64 * 128) + kloff[i]] = rk[h][i];
                *(bf16x8*)&VH[h * (128 * 64) + vloff[i]] = rv[h][i];
            }
        __syncthreads();                 // tile it visible to all waves
        if (it < 17) {                   // prefetch it+1; waited on at next ds_write
            #pragma unroll
            for (int h = 0; h < 2; ++h) {
                const bf16* kp = k + (size_t)(h * 1152 + (it + 1) * 64) * NCI;
                const bf16* vp = v + (h * 1152 + (it + 1) * 64);
                #pragma unroll
                for (int i = 0; i < 4; ++i) {
                    rk[h][i] = *(const bf16x8*)(kp + kgoff[i]);
                    rv[h][i] = *(const bf16x8*)(vp + vgoff[i]);
                }
            }
        }

        // S^T = K * Q^T for 64 m-rows x 32 n-cols (swapped operands, K from LDS)
        f32x16 s0, s1;
        #pragma unroll
        for (int j = 0; j < 16; ++j) { s0[j] = 0.f; s1[j] = 0.f; }

        __builtin_amdgcn_s_setprio(1);
        #pragma unroll
        for (int kq = 0; kq < 8; ++kq) {
            bf16x8 kf0 = *(const bf16x8*)&KB[col * 128 + (((2 * kq + hi) ^ (col & 15)) * 8)];
            s0 = __builtin_amdgcn_mfma_f32_32x32x16_bf16(kf0, qf[kq], s0, 0, 0, 0);
            bf16x8 kf1 = *(const bf16x8*)&KB[(32 + col) * 128 + (((2 * kq + hi) ^ (col & 15)) * 8)];
            s1 = __builtin_amdgcn_mfma_f32_32x32x16_bf16(kf1, qf[kq], s1, 0, 0, 0);
        }
        __builtin_amdgcn_s_setprio(0);

        // sigmoid (in-register) -> bf16 PV B-frags via cvt_pk + permlane32_swap.
        // S^T C-layout: value at reg r = S^T[m = ms*32 + (r&3)+8*(r>>2)+4*hi][n = col].
        // PV B-frag (k-chunk km): elem t = P^T[m = km*16 + 8*hi_dest + t][col].
        union PBu { unsigned int u[4]; bf16x8 v; };
        PBu pb[4];
        #pragma unroll
        for (int ms = 0; ms < 2; ++ms) {
            float p[16];
            #pragma unroll
            for (int r = 0; r < 16; ++r) {
                float sv = (ms == 0) ? s0[r] : s1[r];
                float e = __expf(-sv);
                p[r] = __builtin_amdgcn_rcpf(1.0f + e);
            }
            #pragma unroll
            for (int kst = 0; kst < 2; ++kst) {
                unsigned int a0, a1, b0, b1;
                asm("v_cvt_pk_bf16_f32 %0, %1, %2" : "=v"(a0) : "v"(p[8*kst+0]), "v"(p[8*kst+1]));
                asm("v_cvt_pk_bf16_f32 %0, %1, %2" : "=v"(a1) : "v"(p[8*kst+2]), "v"(p[8*kst+3]));
                asm("v_cvt_pk_bf16_f32 %0, %1, %2" : "=v"(b0) : "v"(p[8*kst+4]), "v"(p[8*kst+5]));
                asm("v_cvt_pk_bf16_f32 %0, %1, %2" : "=v"(b1) : "v"(p[8*kst+6]), "v"(p[8*kst+7]));
                // swap32: a' = {a[0:31], b[0:31]} (w0), b' = {a[32:63], b[32:63]} (w2)
                asm volatile("v_permlane32_swap_b32 %0, %1" : "+v"(a0), "+v"(b0));
                asm volatile("v_permlane32_swap_b32 %0, %1" : "+v"(a1), "+v"(b1));
                pb[ms * 2 + kst].u[0] = a0;
                pb[ms * 2 + kst].u[1] = a1;
                pb[ms * 2 + kst].u[2] = b0;
                pb[ms * 2 + kst].u[3] = b1;
            }
        }

        // O^T += V * P^T (V from LDS as A-frags)
        __builtin_amdgcn_s_setprio(1);
        #pragma unroll
        for (int km = 0; km < 4; ++km) {
            #pragma unroll
            for (int ct = 0; ct < 4; ++ct) {
                bf16x8 vf = *(const bf16x8*)&VB[(ct * 32 + col) * 64 + (((2 * km + hi) ^ (col & 7)) * 8)];
                o[ct] = __builtin_amdgcn_mfma_f32_32x32x16_bf16(vf, pb[km].v, o[ct], 0, 0, 0);
            }
        }
        __builtin_amdgcn_s_setprio(0);
    }

    // Cross-m-half reduction via LDS (reuse KH region), then store.
    // Wave (ns,mh) writes its "other" c-half, reads partner's, stores its own.
    __syncthreads();
    float* RED = (float*)KH;             // 4 buffers of 8 KB: index (ns*2 + src_mh)
    {
        float* buf = RED + (ns * 2 + mh) * 2048;
        int cb = (mh ^ 1) * 2;
        #pragma unroll
        for (int ci = 0; ci < 2; ++ci)
            #pragma unroll
            for (int g = 0; g < 4; ++g) {
                f32x4 val;
                #pragma unroll
                for (int j = 0; j < 4; ++j) val[j] = o[cb + ci][g * 4 + j];
                *(f32x4*)&buf[lane * 32 + (((ci * 4 + g) ^ (lane & 7)) * 4)] = val;
            }
    }
    __syncthreads();
    {
        float* buf = RED + (ns * 2 + (mh ^ 1)) * 2048;
        int cb = mh * 2;
        #pragma unroll
        for (int ci = 0; ci < 2; ++ci)
            #pragma unroll
            for (int g = 0; g < 4; ++g) {
                f32x4 val = *(const f32x4*)&buf[lane * 32 + (((ci * 4 + g) ^ (lane & 7)) * 4)];
                #pragma unroll
                for (int j = 0; j < 4; ++j) o[cb + ci][g * 4 + j] += val[j];
            }
        #pragma unroll
        for (int ci = 0; ci < 2; ++ci) {
            int ct = cb + ci;
            #pragma unroll
            for (int r = 0; r < 16; ++r) {
                int c = ct * 32 + (r & 3) + 8 * (r >> 2) + 4 * hi;
                outy[(size_t)c * NHW + nw + col] = o[ct][r];
            }
        }
    }
}

extern "C" void kernel_launch(void* const* d_in, const int* in_sizes, int n_in,
                              void* d_out, int out_size, void* d_ws, size_t ws_size,
                              hipStream_t stream) {
    const float* x1  = (const float*)d_in[0];
    const float* x2  = (const float*)d_in[1];
    const float* wv1 = (const float*)d_in[2];  const float* bv1 = (const float*)d_in[3];
    const float* wk1 = (const float*)d_in[4];  const float* bk1 = (const float*)d_in[5];
    const float* wq1 = (const float*)d_in[6];  const float* bq1 = (const float*)d_in[7];
    const float* wv2 = (const float*)d_in[8];  const float* bv2 = (const float*)d_in[9];
    const float* wk2 = (const float*)d_in[10]; const float* bk2 = (const float*)d_in[11];
    const float* wq2 = (const float*)d_in[12]; const float* bq2 = (const float*)d_in[13];
    float* out = (float*)d_out;

    // ws layout (bf16): Qt[2][B][2304][128] | Kt | Vt[2][B][128][2304] | wb[6][128*256]
    size_t per = (size_t)2 * NB * NHW * NCI;
    bf16* Qt = (bf16*)d_ws;
    bf16* Kt = Qt + per;
    bf16* Vt = Kt + per;
    bf16* wb = Vt + per;

    wconv_kernel<<<dim3(96), dim3(256), 0, stream>>>(wv1, wk1, wq1, wv2, wk2, wq2, wb);

    qkv_kernel<<<dim3(NB * 2 * NT32), dim3(256), 0, stream>>>(
        x1, x2, wb, bv1, bk1, bq1, bv2, bk2, bq2, Qt, Kt, Vt, out);

    attn_kernel<<<dim3(NB * 2 * 36), dim3(256), 0, stream>>>(Qt, Kt, Vt, out);
}

// Round 2
// 234.868 us; speedup vs baseline: 1.7180x; 1.7180x over previous
//
#include <hip/hip_runtime.h>
#include <hip/hip_bf16.h>

// SCM_39676907888322: sigmoid-gated cross attention. fp32 I/O, bf16 MFMA compute.
// R6: R5 structure (32x32x16 swapped QK^T, in-register P via cvt_pk+permlane32_swap,
// m-split-2 + LDS reduction, XOR-swizzled K/V tiles, reg-double-buffered prefetch)
// with the scratch-spill bugs fixed:
//  - epilogue used o[cb+ci] with RUNTIME cb -> whole f32x16 o[4] accumulator was
//    demoted to scratch for the entire main loop (640 MB HBM writes). Now static:
//    wave-uniform if(mh==0)/else with compile-time indices only.
//  - union PBu type-punning -> u32x4 + __builtin_bit_cast (stays in registers).

typedef __bf16 bf16;
typedef __bf16 bf16x8 __attribute__((ext_vector_type(8)));
typedef __bf16 bf16x4 __attribute__((ext_vector_type(4)));
typedef float f32x4 __attribute__((ext_vector_type(4)));
typedef float f32x16 __attribute__((ext_vector_type(16)));
typedef unsigned int u32x4 __attribute__((ext_vector_type(4)));

#define NB 8
#define NC 256
#define NCI 128
#define NHW 2304
#define NT32 72    // 2304 / 32  (qkv n-tiles)

__global__ __launch_bounds__(256) void wconv_kernel(
    const float* __restrict__ w0, const float* __restrict__ w1,
    const float* __restrict__ w2, const float* __restrict__ w3,
    const float* __restrict__ w4, const float* __restrict__ w5,
    bf16* __restrict__ dst)
{
    int idx = (blockIdx.x * 256 + threadIdx.x) * 8;   // 6*32768 total
    int m = idx >> 15;                                 // matrix id (block-uniform)
    int off = idx & 32767;
    const float* w = (m == 0) ? w0 : (m == 1) ? w1 : (m == 2) ? w2
                   : (m == 3) ? w3 : (m == 4) ? w4 : w5;
    f32x4 a0 = *(const f32x4*)(w + off);
    f32x4 a1 = *(const f32x4*)(w + off + 4);
    bf16x8 o;
    #pragma unroll
    for (int j = 0; j < 4; ++j) { o[j] = (bf16)a0[j]; o[4 + j] = (bf16)a1[j]; }
    *(bf16x8*)(dst + idx) = o;
}

__global__ __launch_bounds__(256) void qkv_kernel(
    const float* __restrict__ x1, const float* __restrict__ x2,
    const bf16* __restrict__ wb,
    const float* __restrict__ bv1, const float* __restrict__ bk1, const float* __restrict__ bq1,
    const float* __restrict__ bv2, const float* __restrict__ bk2, const float* __restrict__ bq2,
    bf16* __restrict__ Qt, bf16* __restrict__ Kt, bf16* __restrict__ Vt,
    float* __restrict__ out)
{
    // Xt[n][c] bf16, 32 rows, padded stride 264
    __shared__ __align__(16) bf16 Xt[32 * 264];

    int gid = blockIdx.x;
    int nt = gid % NT32;
    int s = (gid / NT32) & 1;
    int b = gid / (2 * NT32);
    int n0 = nt * 32;

    const float* x = s ? x2 : x1;
    // wb layout: [v1,k1,q1,v2,k2,q2] each 128*256
    const bf16* wv = wb + (size_t)(s * 3 + 0) * (NCI * NC);
    const bf16* wk = wb + (size_t)(s * 3 + 1) * (NCI * NC);
    const bf16* wq = wb + (size_t)(s * 3 + 2) * (NCI * NC);
    const float* bv = s ? bv2 : bv1;
    const float* bk = s ? bk2 : bk1;
    const float* bq = s ? bq2 : bq1;
    float* outy = out + (size_t)s * (NB * 384 * NHW);

    int tid = threadIdx.x;
    // Stage X tile (256 c x 32 n) into LDS transposed (bf16); fp32 concat passthrough.
    {
        int n_off = (tid & 3) * 8;       // 0,8,16,24
        int c0l = tid >> 2;              // 0..63
        #pragma unroll
        for (int i = 0; i < 4; ++i) {
            int c = c0l + i * 64;
            const float* src = x + ((size_t)(b * NC + c) * NHW + n0 + n_off);
            f32x4 a0 = *(const f32x4*)src;
            f32x4 a1 = *(const f32x4*)(src + 4);
            float* dsty = outy + ((size_t)(b * 384 + c) * NHW + n0 + n_off);
            *(f32x4*)dsty = a0;
            *(f32x4*)(dsty + 4) = a1;
            #pragma unroll
            for (int j = 0; j < 4; ++j) {
                Xt[(n_off + j) * 264 + c] = (bf16)a0[j];
                Xt[(n_off + 4 + j) * 264 + c] = (bf16)a1[j];
            }
        }
    }
    __syncthreads();

    int lane = tid & 63;
    int wid = tid >> 6;                  // wave 0..3 -> ci strip of 32
    int row = lane & 15, quad = lane >> 4;
    int ci_base = wid * 32;

    f32x4 acc[3][2][2];                  // [q,k,v][mi][j]
    #pragma unroll
    for (int t = 0; t < 3; ++t)
        #pragma unroll
        for (int mi = 0; mi < 2; ++mi)
            #pragma unroll
            for (int j = 0; j < 2; ++j)
                acc[t][mi][j] = (f32x4){0.f, 0.f, 0.f, 0.f};

    const bf16* wptr[3] = {wq, wk, wv};
    #pragma unroll
    for (int ks = 0; ks < 8; ++ks) {
        int c0 = ks * 32 + quad * 8;
        bf16x8 bfrag[2];
        #pragma unroll
        for (int j = 0; j < 2; ++j)
            bfrag[j] = *(const bf16x8*)&Xt[(j * 16 + row) * 264 + c0];
        #pragma unroll
        for (int t = 0; t < 3; ++t) {
            #pragma unroll
            for (int mi = 0; mi < 2; ++mi) {
                bf16x8 afrag = *(const bf16x8*)&wptr[t][(size_t)(ci_base + mi * 16 + row) * NC + c0];
                #pragma unroll
                for (int j = 0; j < 2; ++j)
                    acc[t][mi][j] = __builtin_amdgcn_mfma_f32_16x16x32_bf16(
                        afrag, bfrag[j], acc[t][mi][j], 0, 0, 0);
            }
        }
    }

    // Epilogue: +bias (fp32), write Qt/Kt (n,128) bf16 8B stores, V (128,n) bf16 scalar.
    size_t qkbase = ((size_t)s * NB + b) * NHW * NCI;
    size_t vbase  = ((size_t)s * NB + b) * NCI * NHW;
    #pragma unroll
    for (int mi = 0; mi < 2; ++mi) {
        int ci0 = ci_base + mi * 16 + quad * 4;
        f32x4 bq4 = *(const f32x4*)&bq[ci0];
        f32x4 bk4 = *(const f32x4*)&bk[ci0];
        f32x4 bv4 = *(const f32x4*)&bv[ci0];
        #pragma unroll
        for (int j = 0; j < 2; ++j) {
            int n = n0 + j * 16 + row;   // D col = lane&15
            bf16x4 pk;
            #pragma unroll
            for (int r = 0; r < 4; ++r) pk[r] = (bf16)(acc[0][mi][j][r] + bq4[r]);
            *(bf16x4*)&Qt[qkbase + (size_t)n * NCI + ci0] = pk;
            #pragma unroll
            for (int r = 0; r < 4; ++r) pk[r] = (bf16)(acc[1][mi][j][r] + bk4[r]);
            *(bf16x4*)&Kt[qkbase + (size_t)n * NCI + ci0] = pk;
            #pragma unroll
            for (int r = 0; r < 4; ++r)
                Vt[vbase + (size_t)(ci0 + r) * NHW + n] = (bf16)(acc[2][mi][j][r] + bv4[r]);
        }
    }
}

__global__ __launch_bounds__(256, 2) void attn_kernel(
    const bf16* __restrict__ Qt, const bf16* __restrict__ Kt, const bf16* __restrict__ Vt,
    float* __restrict__ out)
{
    // K half-tiles: [2][64 m][128 c] bf16, 16B-chunk swizzle: chunk ^= (mrow & 15)
    // V half-tiles: [2][128 c][64 m] bf16, 16B-chunk swizzle: chunk ^= (crow & 7)
    __shared__ __align__(16) bf16 KH[2 * 64 * 128];   // 32 KB
    __shared__ __align__(16) bf16 VH[2 * 128 * 64];   // 32 KB

    int gid = blockIdx.x;
    // XCD swizzle: gid%8 = XCD slot; both dirs of batch b=gid%8 share an XCD.
    int pair = (gid & 7) * 2 + ((gid >> 3) & 1);   // 0..15
    int nb = gid >> 4;                              // 0..35
    int dir = pair & 1;
    int b = pair >> 1;

    int tid = threadIdx.x;
    int lane = tid & 63;
    int w = tid >> 6;
    int ns = w & 1;        // n-strip (32 rows)
    int mh = w >> 1;       // m-half (m in [mh*1152, mh*1152+1152))
    int col = lane & 31;
    int hi = lane >> 5;

    int sq = dir, skv = dir ^ 1;
    const bf16* q = Qt + ((size_t)sq  * NB + b) * (NHW * NCI);
    const bf16* k = Kt + ((size_t)skv * NB + b) * (NHW * NCI);
    const bf16* v = Vt + ((size_t)skv * NB + b) * (NCI * NHW);
    float* outy = out + (size_t)dir * (NB * 384 * NHW) + ((size_t)b * 384 + 256) * NHW;

    // Staging: per thread 4 chunks (16B) per tile, 4 tiles (K/V x 2 halves).
    int kgoff[4], vgoff[4], kloff[4], vloff[4];
    #pragma unroll
    for (int i = 0; i < 4; ++i) {
        int c = tid + i * 256;
        int kr = c >> 4, kc = c & 15;    // K: 64 rows x 16 chunks
        kgoff[i] = kr * NCI + kc * 8;
        kloff[i] = kr * 128 + ((kc ^ (kr & 15)) * 8);
        int vr = c >> 3, vc = c & 7;     // V: 128 rows x 8 chunks
        vgoff[i] = vr * NHW + vc * 8;
        vloff[i] = vr * 64 + ((vc ^ (vr & 7)) * 8);
    }

    int nw = nb * 64 + ns * 32;          // this wave's 32 Q rows
    bf16x8 qf[8];                        // Q B-frags, resident across m-loop
    #pragma unroll
    for (int kq = 0; kq < 8; ++kq)
        qf[kq] = *(const bf16x8*)&q[(size_t)(nw + col) * NCI + kq * 16 + hi * 8];

    f32x16 o0, o1, o2, o3;               // O^T acc: c-tiles 0..3 (named: static only)
    #pragma unroll
    for (int j = 0; j < 16; ++j) { o0[j] = 0.f; o1[j] = 0.f; o2[j] = 0.f; o3[j] = 0.f; }

    // Prefetch tile 0 (both halves) into registers.
    bf16x8 rk[2][4], rv[2][4];
    #pragma unroll
    for (int h = 0; h < 2; ++h) {
        const bf16* kp = k + (size_t)(h * 1152) * NCI;
        const bf16* vp = v + h * 1152;
        #pragma unroll
        for (int i = 0; i < 4; ++i) {
            rk[h][i] = *(const bf16x8*)(kp + kgoff[i]);
            rv[h][i] = *(const bf16x8*)(vp + vgoff[i]);
        }
    }

    const bf16* KB = &KH[mh * (64 * 128)];
    const bf16* VB = &VH[mh * (128 * 64)];

    for (int it = 0; it < 18; ++it) {
        __syncthreads();                 // prior tile's LDS reads complete
        #pragma unroll
        for (int h = 0; h < 2; ++h)
            #pragma unroll
            for (int i = 0; i < 4; ++i) {
                *(bf16x8*)&KH[h * (64 * 128) + kloff[i]] = rk[h][i];
                *(bf16x8*)&VH[h * (128 * 64) + vloff[i]] = rv[h][i];
            }
        __syncthreads();                 // tile it visible to all waves
        if (it < 17) {                   // prefetch it+1; waited on at next ds_write
            #pragma unroll
            for (int h = 0; h < 2; ++h) {
                const bf16* kp = k + (size_t)(h * 1152 + (it + 1) * 64) * NCI;
                const bf16* vp = v + (h * 1152 + (it + 1) * 64);
                #pragma unroll
                for (int i = 0; i < 4; ++i) {
                    rk[h][i] = *(const bf16x8*)(kp + kgoff[i]);
                    rv[h][i] = *(const bf16x8*)(vp + vgoff[i]);
                }
            }
        }

        // S^T = K * Q^T for 64 m-rows x 32 n-cols (swapped operands, K from LDS)
        f32x16 s0, s1;
        #pragma unroll
        for (int j = 0; j < 16; ++j) { s0[j] = 0.f; s1[j] = 0.f; }

        __builtin_amdgcn_s_setprio(1);
        #pragma unroll
        for (int kq = 0; kq < 8; ++kq) {
            bf16x8 kf0 = *(const bf16x8*)&KB[col * 128 + (((2 * kq + hi) ^ (col & 15)) * 8)];
            s0 = __builtin_amdgcn_mfma_f32_32x32x16_bf16(kf0, qf[kq], s0, 0, 0, 0);
            bf16x8 kf1 = *(const bf16x8*)&KB[(32 + col) * 128 + (((2 * kq + hi) ^ (col & 15)) * 8)];
            s1 = __builtin_amdgcn_mfma_f32_32x32x16_bf16(kf1, qf[kq], s1, 0, 0, 0);
        }
        __builtin_amdgcn_s_setprio(0);

        // sigmoid (in-register) -> bf16 PV B-frags via cvt_pk + permlane32_swap.
        // S^T C-layout: value at reg r = S^T[m = ms*32 + (r&3)+8*(r>>2)+4*hi][n = col].
        // PV B-frag (k-chunk km): elem t = P^T[m = km*16 + 8*hi_dest + t][col].
        u32x4 pbw[4];                    // bit-cast to bf16x8 at use (no union!)
        #pragma unroll
        for (int ms = 0; ms < 2; ++ms) {
            float p[16];
            #pragma unroll
            for (int r = 0; r < 16; ++r) {
                float sv = (ms == 0) ? s0[r] : s1[r];
                float e = __expf(-sv);
                p[r] = __builtin_amdgcn_rcpf(1.0f + e);
            }
            #pragma unroll
            for (int kst = 0; kst < 2; ++kst) {
                unsigned int a0, a1, b0, b1;
                asm("v_cvt_pk_bf16_f32 %0, %1, %2" : "=v"(a0) : "v"(p[8*kst+0]), "v"(p[8*kst+1]));
                asm("v_cvt_pk_bf16_f32 %0, %1, %2" : "=v"(a1) : "v"(p[8*kst+2]), "v"(p[8*kst+3]));
                asm("v_cvt_pk_bf16_f32 %0, %1, %2" : "=v"(b0) : "v"(p[8*kst+4]), "v"(p[8*kst+5]));
                asm("v_cvt_pk_bf16_f32 %0, %1, %2" : "=v"(b1) : "v"(p[8*kst+6]), "v"(p[8*kst+7]));
                // swap32: a' = {a[0:31], b[0:31]} (w0), b' = {a[32:63], b[32:63]} (w2)
                asm volatile("v_permlane32_swap_b32 %0, %1" : "+v"(a0), "+v"(b0));
                asm volatile("v_permlane32_swap_b32 %0, %1" : "+v"(a1), "+v"(b1));
                pbw[ms * 2 + kst] = (u32x4){a0, a1, b0, b1};
            }
        }

        // O^T += V * P^T (V from LDS as A-frags)
        __builtin_amdgcn_s_setprio(1);
        #pragma unroll
        for (int km = 0; km < 4; ++km) {
            bf16x8 pf = __builtin_bit_cast(bf16x8, pbw[km]);
            {
                bf16x8 vf = *(const bf16x8*)&VB[(0 * 32 + col) * 64 + (((2 * km + hi) ^ (col & 7)) * 8)];
                o0 = __builtin_amdgcn_mfma_f32_32x32x16_bf16(vf, pf, o0, 0, 0, 0);
            }
            {
                bf16x8 vf = *(const bf16x8*)&VB[(1 * 32 + col) * 64 + (((2 * km + hi) ^ (col & 7)) * 8)];
                o1 = __builtin_amdgcn_mfma_f32_32x32x16_bf16(vf, pf, o1, 0, 0, 0);
            }
            {
                bf16x8 vf = *(const bf16x8*)&VB[(2 * 32 + col) * 64 + (((2 * km + hi) ^ (col & 7)) * 8)];
                o2 = __builtin_amdgcn_mfma_f32_32x32x16_bf16(vf, pf, o2, 0, 0, 0);
            }
            {
                bf16x8 vf = *(const bf16x8*)&VB[(3 * 32 + col) * 64 + (((2 * km + hi) ^ (col & 7)) * 8)];
                o3 = __builtin_amdgcn_mfma_f32_32x32x16_bf16(vf, pf, o3, 0, 0, 0);
            }
        }
        __builtin_amdgcn_s_setprio(0);
    }

    // Cross-m-half reduction via LDS (reuse KH region), then store.
    // Wave (ns,mh) writes its "other" c-half, reads partner's, stores its own.
    // All o indices are COMPILE-TIME; mh branches are wave-uniform, barriers outside.
    float* RED = (float*)KH;             // 4 buffers of 8 KB: index (ns*2 + src_mh)

    auto red_write = [&](float* buf, const f32x16 oa, const f32x16 ob) {
        #pragma unroll
        for (int g = 0; g < 4; ++g) {
            f32x4 va, vb;
            #pragma unroll
            for (int j = 0; j < 4; ++j) { va[j] = oa[g * 4 + j]; vb[j] = ob[g * 4 + j]; }
            *(f32x4*)&buf[lane * 32 + ((g ^ (lane & 7)) * 4)] = va;
            *(f32x4*)&buf[lane * 32 + (((4 + g) ^ (lane & 7)) * 4)] = vb;
        }
    };
    auto red_fin = [&](float* buf, f32x16& oa, f32x16& ob, int ctbase) {
        #pragma unroll
        for (int g = 0; g < 4; ++g) {
            f32x4 va = *(const f32x4*)&buf[lane * 32 + ((g ^ (lane & 7)) * 4)];
            f32x4 vb = *(const f32x4*)&buf[lane * 32 + (((4 + g) ^ (lane & 7)) * 4)];
            #pragma unroll
            for (int j = 0; j < 4; ++j) { oa[g * 4 + j] += va[j]; ob[g * 4 + j] += vb[j]; }
        }
        #pragma unroll
        for (int r = 0; r < 16; ++r) {
            int cr = (r & 3) + 8 * (r >> 2) + 4 * hi;
            outy[(size_t)(ctbase * 32 + cr) * NHW + nw + col] = oa[r];
            outy[(size_t)((ctbase + 1) * 32 + cr) * NHW + nw + col] = ob[r];
        }
    };

    __syncthreads();
    if (mh == 0) red_write(RED + (ns * 2 + 0) * 2048, o2, o3);
    else         red_write(RED + (ns * 2 + 1) * 2048, o0, o1);
    __syncthreads();
    if (mh == 0) red_fin(RED + (ns * 2 + 1) * 2048, o0, o1, 0);
    else         red_fin(RED + (ns * 2 + 0) * 2048, o2, o3, 2);
}

extern "C" void kernel_launch(void* const* d_in, const int* in_sizes, int n_in,
                              void* d_out, int out_size, void* d_ws, size_t ws_size,
                              hipStream_t stream) {
    const float* x1  = (const float*)d_in[0];
    const float* x2  = (const float*)d_in[1];
    const float* wv1 = (const float*)d_in[2];  const float* bv1 = (const float*)d_in[3];
    const float* wk1 = (const float*)d_in[4];  const float* bk1 = (const float*)d_in[5];
    const float* wq1 = (const float*)d_in[6];  const float* bq1 = (const float*)d_in[7];
    const float* wv2 = (const float*)d_in[8];  const float* bv2 = (const float*)d_in[9];
    const float* wk2 = (const float*)d_in[10]; const float* bk2 = (const float*)d_in[11];
    const float* wq2 = (const float*)d_in[12]; const float* bq2 = (const float*)d_in[13];
    float* out = (float*)d_out;

    // ws layout (bf16): Qt[2][B][2304][128] | Kt | Vt[2][B][128][2304] | wb[6][128*256]
    size_t per = (size_t)2 * NB * NHW * NCI;
    bf16* Qt = (bf16*)d_ws;
    bf16* Kt = Qt + per;
    bf16* Vt = Kt + per;
    bf16* wb = Vt + per;

    wconv_kernel<<<dim3(96), dim3(256), 0, stream>>>(wv1, wk1, wq1, wv2, wk2, wq2, wb);

    qkv_kernel<<<dim3(NB * 2 * NT32), dim3(256), 0, stream>>>(
        x1, x2, wb, bv1, bk1, bq1, bv2, bk2, bq2, Qt, Kt, Vt, out);

    attn_kernel<<<dim3(NB * 2 * 36), dim3(256), 0, stream>>>(Qt, Kt, Vt, out);
}